// Round 1
// baseline (74.435 us; speedup 1.0000x reference)
//
#include <hip/hip_runtime.h>
#include <math.h>

// Echellogram: out[x,y] = emask*sky + src_prof*src + bkg
// sky/src = sum_a exp(-0.5*((lam(x,y)-lam_vector[a])/0.42)^2) * norm * {amps,src_amps}[a]
//
// lam_vector is a uniform linspace (spacing dlam ~0.215, sigma=0.42).
// 1) 5.5-sigma window truncation (tail <= ~5e-5, invisible vs the ~43 absmax
//    threshold; measured fp32-vs-np error is already ~8).
// 2) Uniform-grid Gaussian recurrence: with d = dlam/sigma,
//      exp(-0.5*(z0 -/+ k*d)^2) follows u_{k+1}=u_k*v_k, v_{k+1}=v_k*w,
//      w = exp(-d^2), v0 = exp(+/-z0*d - 0.5*d^2).
//    Replaces 23 __expf + 3 gathers/iter with 2 __expf + 1 div per pixel
//    and 2 gathers + 2 mul + 2 fma per iter.

#define NXd 1024
#define NYd 85
#define NAMPS 1500

__global__ __launch_bounds__(256) void echell_kernel(
    const int*   __restrict__ index_p,
    const float* __restrict__ bkg_p,
    const float* __restrict__ s_coeffs,
    const float* __restrict__ amps,
    const float* __restrict__ smooth_p,
    const float* __restrict__ lam_c,
    const float* __restrict__ p_coeffs,
    const float* __restrict__ src_amps,
    const float* __restrict__ fiducial,
    const float* __restrict__ lam_vector,
    float*       __restrict__ out)
{
    int t = blockIdx.x * blockDim.x + threadIdx.x;
    if (t >= NXd * NYd) return;
    int xi = t / NYd;
    int yi = t - xi * NYd;
    float xx = (float)xi, yy = (float)yi;

    // along-slit coordinate
    float ss = s_coeffs[1] * (yy - s_coeffs[0] - s_coeffs[2] * xx);

    // wavelength surface
    float xn = (xx - 512.0f) * (1.0f / 512.0f);
    float yn = (yy - 42.5f) * (1.0f / 42.5f);
    float cx1 = fiducial[1] * (1.0f + lam_c[1] * 0.01f) * 512.0f;
    float cx2 = 1.0f + lam_c[2];
    float lam = fiducial[0] + lam_c[0] + cx1 * xn
              + cx2 * (2.0f * xn * xn - 1.0f) + lam_c[3] * yn;

    // soft slit mask
    float inv_beta = __expf(-smooth_p[0]);
    float e1 = 1.0f / (1.0f + __expf(-ss * inv_beta));
    float e2 = 1.0f / (1.0f + __expf(-(12.0f - ss) * inv_beta));
    float emask = e1 * e2;

    // window geometry
    float lam0 = lam_vector[0];
    float lamN = lam_vector[NAMPS - 1];
    float span = lamN - lam0;
    float dlam = span * (1.0f / (float)(NAMPS - 1));
    float inv_dlam = (float)(NAMPS - 1) / span;

    int i0 = (int)floorf((lam - lam0) * inv_dlam + 0.5f);
    i0 = i0 < 0 ? 0 : (i0 > NAMPS - 1 ? NAMPS - 1 : i0);

    const float inv_sig = 1.0f / 0.42f;
    float d  = dlam * inv_sig;                     // ~0.513 z-units per index
    float w  = __expf(-d * d);                     // uniform ratio-of-ratios
    float z0 = (lam - lam_vector[i0]) * inv_sig;   // |z0| <= d/2 (+clamp eps)

    float u0 = __expf(-0.5f * z0 * z0);
    float vp = __expf(fmaf(z0, d, -0.5f * d * d)); // exp(z0*d - d^2/2)
    float vm = w / vp;                             // exp(-z0*d - d^2/2)

    int Wn = (int)ceilf(2.31f * inv_dlam);         // 5.5 sigma in index units
    if (Wn > NAMPS - 1) Wn = NAMPS - 1;
    int kup = NAMPS - 1 - i0; if (kup > Wn) kup = Wn;
    int kdn = i0;             if (kdn > Wn) kdn = Wn;

    // center term
    float sky = u0 * amps[i0];
    float src = u0 * src_amps[i0];

    // upward sweep: j = i0+k, pdf = u0 * exp(z0*d*k - 0.5*d^2*k^2)
    float u = u0 * vp, v = vp * w;
    #pragma unroll 4
    for (int k = 1; k <= kup; ++k) {
        sky = fmaf(u, amps[i0 + k], sky);
        src = fmaf(u, src_amps[i0 + k], src);
        u *= v; v *= w;
    }
    // downward sweep: j = i0-k
    u = u0 * vm; v = vm * w;
    #pragma unroll 4
    for (int k = 1; k <= kdn; ++k) {
        sky = fmaf(u, amps[i0 - k], sky);
        src = fmaf(u, src_amps[i0 - k], src);
        u *= v; v *= w;
    }

    const float norm = 0.3989422804014327f * inv_sig;  // 1/sqrt(2pi)/sigma
    sky *= norm;
    src *= norm;

    // source spatial profile
    int idx = index_p[0];
    float p0 = p_coeffs[2 * idx];
    float p1 = p_coeffs[2 * idx + 1];
    float sigma = __expf(p1);
    float zz = (ss - p0) / sigma;
    float src_prof = __expf(-0.5f * zz * zz - p1 - 0.9189385332046727f);

    out[t] = emask * sky + src_prof * src + bkg_p[0];
}

extern "C" void kernel_launch(void* const* d_in, const int* in_sizes, int n_in,
                              void* d_out, int out_size, void* d_ws, size_t ws_size,
                              hipStream_t stream) {
    const int*   index_p    = (const int*)  d_in[0];
    const float* bkg_p      = (const float*)d_in[1];
    const float* s_coeffs   = (const float*)d_in[2];
    const float* amps       = (const float*)d_in[3];
    const float* smooth_p   = (const float*)d_in[4];
    const float* lam_c      = (const float*)d_in[5];
    const float* p_coeffs   = (const float*)d_in[6];
    const float* src_amps   = (const float*)d_in[7];
    const float* fiducial   = (const float*)d_in[8];
    const float* lam_vector = (const float*)d_in[9];
    float* out = (float*)d_out;

    const int total = NXd * NYd;                   // 87040
    const int block = 256;
    const int grid = (total + block - 1) / block;  // 340
    echell_kernel<<<grid, block, 0, stream>>>(
        index_p, bkg_p, s_coeffs, amps, smooth_p, lam_c,
        p_coeffs, src_amps, fiducial, lam_vector, out);
}